// Round 1
// baseline (177.715 us; speedup 1.0000x reference)
//
#include <hip/hip_runtime.h>
#include <hip/hip_bf16.h>

// Fused attention: q = x1@W^T+b, k = x2@W^T+b, scores = (q k^T)*sqrt(64),
// p = softmax(scores), out = p @ x2.  B=4, S=T=4096, F=127, D=64, fp32 io.
//
// Design (round 0):
//  - proj_kernel: Q fp32 (x8 scale folded in, exact), K split to bf16 hi/lo.
//  - x2t_kernel: x2 -> bf16 transposed [128][4096] (row 127 zero-padded).
//  - attn_kernel: flash-style. 512 blocks x 4 waves; block = 32 q-rows;
//    each wave owns a strided 1/4 of key tiles with private online softmax,
//    merged in LDS at the end (deterministic). QK^T via 3x split-bf16 MFMA
//    (logit err ~1e-3), PV via bf16 MFMA on out^T = x2^T * P^T; P converted
//    in-register with v_cvt_pk_bf16_f32 + v_permlane32_swap_b32.
//
// ws layout (12 MB total): Qf32 [0,4MB) | kh [4,6) | kl [6,8) | x2t [8,12)

typedef __bf16 bf16x8 __attribute__((ext_vector_type(8)));
typedef float f32x16 __attribute__((ext_vector_type(16)));

#define S_DIM 4096
#define F_DIM 127

static __device__ __forceinline__ unsigned short f2bf(float f) {
  unsigned u = __float_as_uint(f);
  unsigned r = u + 0x7FFFu + ((u >> 16) & 1u);  // RNE, no NaN in our data
  return (unsigned short)(r >> 16);
}
static __device__ __forceinline__ float bf2f(unsigned short h) {
  return __uint_as_float(((unsigned)h) << 16);
}
static __device__ __forceinline__ unsigned cvt_pk_bf16(float lo, float hi) {
  unsigned r;
  asm("v_cvt_pk_bf16_f32 %0, %1, %2" : "=v"(r) : "v"(lo), "v"(hi));
  return r;
}
static __device__ __forceinline__ bf16x8 mk_bf16x8(unsigned w0, unsigned w1,
                                                   unsigned w2, unsigned w3) {
  unsigned t[4] = {w0, w1, w2, w3};
  bf16x8 r;
  __builtin_memcpy(&r, t, 16);
  return r;
}

// ---------------------------------------------------------------- projection
// grid 2048 x 256: blocks [0,1024) -> Q from x1, [1024,2048) -> K from x2.
// 16 rows per block. Wt staged transposed in LDS (conflict-free reads).
__global__ __launch_bounds__(256) void proj_kernel(
    const float* __restrict__ x1, const float* __restrict__ x2,
    const float* __restrict__ W, const float* __restrict__ bias,
    float* __restrict__ Qf, unsigned short* __restrict__ kh,
    unsigned short* __restrict__ kl) {
  __shared__ float Wt[F_DIM * 64];  // Wt[f*64+d]
  __shared__ float xr[16][128];
  const int tid = threadIdx.x;
  const int bi = blockIdx.x;
  const bool isK = bi >= 1024;
  const int blk = isK ? (bi - 1024) : bi;
  const long r0 = (long)blk * 16;
  const float* x = isK ? x2 : x1;

  for (int idx = tid; idx < 64 * F_DIM; idx += 256) {
    int d = idx / F_DIM;
    int f = idx - d * F_DIM;
    Wt[f * 64 + d] = W[idx];
  }
  const float* xb = x + r0 * F_DIM;
  for (int idx = tid; idx < 16 * F_DIM; idx += 256) {
    int r = idx / F_DIM;
    int f = idx - r * F_DIM;
    xr[r][f] = xb[idx];
  }
  __syncthreads();

  const int d = tid & 63;
  const int wv = tid >> 6;
  const float bd = bias[d];
  for (int i = 0; i < 4; ++i) {
    const int r = wv * 4 + i;
    float acc = 0.f;
#pragma unroll
    for (int f = 0; f < F_DIM; ++f) acc = fmaf(xr[r][f], Wt[f * 64 + d], acc);
    const float val = acc + bd;
    const long o = (r0 + r) * 64 + d;
    if (!isK) {
      Qf[o] = val * 8.0f;  // fold scores*sqrt(D)=8 here (exact)
    } else {
      unsigned short h = f2bf(val);
      kh[o] = h;
      kl[o] = f2bf(val - bf2f(h));
    }
  }
}

// ------------------------------------------------------------- x2 transpose
// grid 512 x 256: block = batch b, 32 t-rows. Out layout x2t[b][f 128][t 4096].
__global__ __launch_bounds__(256) void x2t_kernel(
    const float* __restrict__ x2, unsigned short* __restrict__ x2t) {
  __shared__ float tile[32][129];
  const int tid = threadIdx.x;
  const int bi = blockIdx.x;
  const int b = bi >> 7;
  const int t0 = (bi & 127) << 5;
  const float* src = x2 + ((long)b * S_DIM + t0) * F_DIM;
  for (int idx = tid; idx < 32 * F_DIM; idx += 256) {
    int r = idx / F_DIM;
    int f = idx - r * F_DIM;
    tile[r][f] = src[idx];
  }
  __syncthreads();
  const int c = tid & 31;
  const int fq = tid >> 5;
  unsigned short* dst = x2t + (long)b * 128 * S_DIM + t0 + c;
#pragma unroll
  for (int j = 0; j < 16; ++j) {
    const int f = fq * 16 + j;
    const float v = (f < F_DIM) ? tile[c][f] : 0.f;  // pad f=127 with zeros
    dst[(long)f * S_DIM] = f2bf(v);
  }
}

// ------------------------------------------------------------------ attention
// grid 512 x 256. block: b = bi>>7, q-rows [q0, q0+32). wave w handles key
// tiles w, w+4, ..., w+124 (32 tiles of 32 keys) with private (m, l, acc).
__global__ __launch_bounds__(256) void attn_kernel(
    const float* __restrict__ Qf, const unsigned short* __restrict__ kh,
    const unsigned short* __restrict__ kl,
    const unsigned short* __restrict__ x2t, float* __restrict__ out) {
  const int tid = threadIdx.x;
  const int lane = tid & 63;
  const int wave = tid >> 6;
  const int col = lane & 31;   // q index within tile / key row for A-frag
  const int half = lane >> 5;  // k-group select
  const int bi = blockIdx.x;
  const int b = bi >> 7;
  const int q0 = (bi & 127) << 5;

  // Q B-fragments (col=q=lane&31, k = kk*16 + half*8 + j), split hi/lo
  bf16x8 qh[4], ql[4];
  {
    const float* qrow = Qf + ((long)(b * S_DIM + q0 + col)) * 64;
#pragma unroll
    for (int kk = 0; kk < 4; ++kk) {
      const int d0 = kk * 16 + half * 8;
      unsigned short hs[8], ls[8];
#pragma unroll
      for (int j = 0; j < 8; ++j) {
        const float qv = qrow[d0 + j];
        const unsigned short h = f2bf(qv);
        hs[j] = h;
        ls[j] = f2bf(qv - bf2f(h));
      }
      __builtin_memcpy(&qh[kk], hs, 16);
      __builtin_memcpy(&ql[kk], ls, 16);
    }
  }

  const uint4* khp = (const uint4*)kh + (long)b * S_DIM * 8;  // 8 uint4/key
  const uint4* klp = (const uint4*)kl + (long)b * S_DIM * 8;
  const uint4* xp = (const uint4*)x2t + (long)b * 128 * (S_DIM / 8);

  f32x16 a0, a1, a2, a3;
#pragma unroll
  for (int r = 0; r < 16; ++r) {
    a0[r] = 0.f; a1[r] = 0.f; a2[r] = 0.f; a3[r] = 0.f;
  }
  float m = -INFINITY;
  float lsum = 0.f;

  for (int it = 0; it < 32; ++it) {
    const int t0 = ((it << 2) + wave) << 5;
    const int key = t0 + col;
    uint4 khf[4], klf[4];
#pragma unroll
    for (int kk = 0; kk < 4; ++kk) {
      khf[kk] = khp[key * 8 + kk * 2 + half];
      klf[kk] = klp[key * 8 + kk * 2 + half];
    }
    // S^T = K . Q^T  (3-term split-bf16), C layout: col=q, row=key
    f32x16 st;
#pragma unroll
    for (int r = 0; r < 16; ++r) st[r] = 0.f;
#pragma unroll
    for (int kk = 0; kk < 4; ++kk) {
      bf16x8 kv, lv;
      __builtin_memcpy(&kv, &khf[kk], 16);
      __builtin_memcpy(&lv, &klf[kk], 16);
      st = __builtin_amdgcn_mfma_f32_32x32x16_bf16(kv, qh[kk], st, 0, 0, 0);
      st = __builtin_amdgcn_mfma_f32_32x32x16_bf16(kv, ql[kk], st, 0, 0, 0);
      st = __builtin_amdgcn_mfma_f32_32x32x16_bf16(lv, qh[kk], st, 0, 0, 0);
    }
    // online softmax: lane's 16 regs = 16 keys of its q-col; other 16 keys
    // are in lane^32 -> one shfl_xor completes the row reduce.
    float pmax = st[0];
#pragma unroll
    for (int r = 1; r < 16; ++r) pmax = fmaxf(pmax, st[r]);
    pmax = fmaxf(pmax, __shfl_xor(pmax, 32));
    const float mnew = fmaxf(m, pmax);
    const float scale = __expf(m - mnew);  // first tile: exp(-inf)=0
    float p[16];
    float ts = 0.f;
#pragma unroll
    for (int r = 0; r < 16; ++r) {
      p[r] = __expf(st[r] - mnew);
      ts += p[r];
    }
    ts += __shfl_xor(ts, 32);
    lsum = lsum * scale + ts;
    m = mnew;
#pragma unroll
    for (int r = 0; r < 16; ++r) {
      a0[r] *= scale; a1[r] *= scale; a2[r] *= scale; a3[r] *= scale;
    }
    // pack P rows (C-layout regs) into PV B-fragments:
    // frag[kk] elem j needs reg 8kk+4h+(j&3) from half (j>=4) of same col
    // -> exactly one permlane32_swap pair per kk.
    unsigned pg[4][2];
#pragma unroll
    for (int g = 0; g < 4; ++g) {
      pg[g][0] = cvt_pk_bf16(p[4 * g + 0], p[4 * g + 1]);
      pg[g][1] = cvt_pk_bf16(p[4 * g + 2], p[4 * g + 3]);
    }
#pragma unroll
    for (int kk = 0; kk < 2; ++kk) {
      unsigned x0 = pg[2 * kk][0], y0 = pg[2 * kk + 1][0];
      unsigned x1 = pg[2 * kk][1], y1 = pg[2 * kk + 1][1];
      asm("v_permlane32_swap_b32 %0, %1" : "+v"(x0), "+v"(y0));
      asm("v_permlane32_swap_b32 %0, %1" : "+v"(x1), "+v"(y1));
      const bf16x8 pf = mk_bf16x8(x0, x1, y0, y1);
      const int tof = (t0 + kk * 16 + half * 8) >> 3;  // uint4 idx in f-row
      bf16x8 xf;
      uint4 xv;
      xv = xp[(0 * 32 + col) * (S_DIM / 8) + tof];
      __builtin_memcpy(&xf, &xv, 16);
      a0 = __builtin_amdgcn_mfma_f32_32x32x16_bf16(xf, pf, a0, 0, 0, 0);
      xv = xp[(1 * 32 + col) * (S_DIM / 8) + tof];
      __builtin_memcpy(&xf, &xv, 16);
      a1 = __builtin_amdgcn_mfma_f32_32x32x16_bf16(xf, pf, a1, 0, 0, 0);
      xv = xp[(2 * 32 + col) * (S_DIM / 8) + tof];
      __builtin_memcpy(&xf, &xv, 16);
      a2 = __builtin_amdgcn_mfma_f32_32x32x16_bf16(xf, pf, a2, 0, 0, 0);
      xv = xp[(3 * 32 + col) * (S_DIM / 8) + tof];
      __builtin_memcpy(&xf, &xv, 16);
      a3 = __builtin_amdgcn_mfma_f32_32x32x16_bf16(xf, pf, a3, 0, 0, 0);
    }
  }

  // -------- merge the 4 waves' partial (m, l, acc^T) in LDS, then write out
  __shared__ float mbuf[4][32];
  __shared__ float lbuf[4][32];
  __shared__ float accbuf[128][32];  // [f][q]
  if (lane < 32) {
    mbuf[wave][col] = m;
    lbuf[wave][col] = lsum;
  }
  __syncthreads();
  const float mstar = fmaxf(fmaxf(mbuf[0][col], mbuf[1][col]),
                            fmaxf(mbuf[2][col], mbuf[3][col]));
  const float wsc = __expf(m - mstar);
  for (int w = 0; w < 4; ++w) {
    if (wave == w) {
#pragma unroll
      for (int fb = 0; fb < 4; ++fb) {
        const f32x16 av = (fb == 0) ? a0 : (fb == 1) ? a1 : (fb == 2) ? a2 : a3;
#pragma unroll
        for (int r = 0; r < 16; ++r) {
          const int f = fb * 32 + ((r & 3) + 8 * (r >> 2) + 4 * half);
          const float v = av[r] * wsc;
          if (w == 0) accbuf[f][col] = v;
          else accbuf[f][col] += v;
        }
      }
    }
    __syncthreads();
  }
  const int q = tid >> 3;
  const int fg = tid & 7;
  const float ms2 = fmaxf(fmaxf(mbuf[0][q], mbuf[1][q]),
                          fmaxf(mbuf[2][q], mbuf[3][q]));
  float lst = 0.f;
#pragma unroll
  for (int w = 0; w < 4; ++w) lst += lbuf[w][q] * __expf(mbuf[w][q] - ms2);
  const float inv = 1.0f / lst;
  float* ob = out + ((long)(b * S_DIM + q0 + q)) * F_DIM;
#pragma unroll
  for (int j = 0; j < 16; ++j) {
    const int f = fg * 16 + j;
    if (f < F_DIM) ob[f] = accbuf[f][q] * inv;
  }
}

extern "C" void kernel_launch(void* const* d_in, const int* in_sizes, int n_in,
                              void* d_out, int out_size, void* d_ws,
                              size_t ws_size, hipStream_t stream) {
  const float* x1 = (const float*)d_in[0];
  const float* x2 = (const float*)d_in[1];
  const float* W = (const float*)d_in[2];
  const float* bias = (const float*)d_in[3];
  float* out = (float*)d_out;

  char* ws = (char*)d_ws;
  float* Qf = (float*)ws;                                   // 4 MB
  unsigned short* kh = (unsigned short*)(ws + (4l << 20));  // 2 MB
  unsigned short* kl = (unsigned short*)(ws + (6l << 20));  // 2 MB
  unsigned short* x2t = (unsigned short*)(ws + (8l << 20)); // 4 MB

  hipLaunchKernelGGL(proj_kernel, dim3(2048), dim3(256), 0, stream, x1, x2, W,
                     bias, Qf, kh, kl);
  hipLaunchKernelGGL(x2t_kernel, dim3(512), dim3(256), 0, stream, x2, x2t);
  hipLaunchKernelGGL(attn_kernel, dim3(512), dim3(256), 0, stream, Qf, kh, kl,
                     x2t, out);
}

// Round 2
// 169.810 us; speedup vs baseline: 1.0465x; 1.0465x over previous
//
#include <hip/hip_runtime.h>
#include <hip/hip_bf16.h>

// Fused attention: q = x1@W^T+b, k = x2@W^T+b, scores = (q k^T)*8,
// p = softmax(scores), out = p @ x2.  B=4, S=T=4096, F=127, D=64, fp32 io.
//
// Round 1:
//  - proj_kernel: split-bf16 MFMA GEMM (3-term). Q written fp32 with
//    8*log2(e) folded (softmax runs in exp2 domain). K written as bf16
//    hi/lo. K-side blocks also emit x2t (bf16, transposed, f=127 padded)
//    straight from their A-fragments -> old x2t kernel deleted.
//  - attn_kernel: 512 threads (8 waves), each wave 16 key-tiles of 32,
//    private online softmax in log2 domain with defer-max (THR=11),
//    LDS tree-merge (2 buffers, 4 barriers).
//
// ws layout: Qf32 [0,4MB) | kh [4,6) | kl [6,8) | x2t [8,12)

typedef __bf16 bf16x8 __attribute__((ext_vector_type(8)));
typedef float f32x16 __attribute__((ext_vector_type(16)));

#define S_DIM 4096
#define F_DIM 127
#define QSCALE 11.5415603271f  // 8 * log2(e)
#define THR 11.0f              // defer-max threshold (log2 units) -> P <= 2048

static __device__ __forceinline__ unsigned short f2bf(float f) {
  unsigned u = __float_as_uint(f);
  unsigned r = u + 0x7FFFu + ((u >> 16) & 1u);  // RNE, no NaN in our data
  return (unsigned short)(r >> 16);
}
static __device__ __forceinline__ float bf2f(unsigned short h) {
  return __uint_as_float(((unsigned)h) << 16);
}
static __device__ __forceinline__ unsigned cvt_pk_bf16(float lo, float hi) {
  unsigned r;
  asm("v_cvt_pk_bf16_f32 %0, %1, %2" : "=v"(r) : "v"(lo), "v"(hi));
  return r;
}
static __device__ __forceinline__ float exp2_fast(float x) {
  float r;
  asm("v_exp_f32 %0, %1" : "=v"(r) : "v"(x));
  return r;
}
static __device__ __forceinline__ bf16x8 mk_bf16x8(unsigned w0, unsigned w1,
                                                   unsigned w2, unsigned w3) {
  unsigned t[4] = {w0, w1, w2, w3};
  bf16x8 r;
  __builtin_memcpy(&r, t, 16);
  return r;
}

// ---------------------------------------------------------------- projection
// grid 256 x 256. blocks [0,128) -> Q from x1, [128,256) -> K from x2.
// Block = 128 rows (4 waves x 32). Per wave: acc[32 rows][64 d] via
// 8 K-steps x 3 split-MFMA x 2 d-tiles = 48 MFMA. No LDS.
__global__ __launch_bounds__(256) void proj_kernel(
    const float* __restrict__ x1, const float* __restrict__ x2,
    const float* __restrict__ W, const float* __restrict__ bias,
    float* __restrict__ Qf, unsigned short* __restrict__ kh,
    unsigned short* __restrict__ kl, unsigned short* __restrict__ x2t) {
  const int tid = threadIdx.x;
  const int wave = tid >> 6;
  const int lane = tid & 63;
  const int arow = lane & 31;
  const int half = lane >> 5;
  const int bi = blockIdx.x;
  const bool isK = bi >= 128;
  const float* x = isK ? x2 : x1;
  const int grow0 = (bi & 127) * 128 + wave * 32;
  const float* xrow = x + (long)(grow0 + arow) * F_DIM;

  // A-fragments: x[row][k], row=lane&31, k = kk*16 + half*8 + j. Split hi/lo.
  bf16x8 xh[8], xl[8];
#pragma unroll
  for (int kk = 0; kk < 8; ++kk) {
    unsigned short hs[8], ls[8];
#pragma unroll
    for (int j = 0; j < 8; ++j) {
      const int f = kk * 16 + half * 8 + j;
      const float v = (f < F_DIM) ? xrow[f] : 0.f;
      const unsigned short h = f2bf(v);
      hs[j] = h;
      ls[j] = f2bf(v - bf2f(h));
    }
    __builtin_memcpy(&xh[kk], hs, 16);
    __builtin_memcpy(&xl[kk], ls, 16);
  }

  f32x16 acc0, acc1;
#pragma unroll
  for (int r = 0; r < 16; ++r) {
    acc0[r] = 0.f;
    acc1[r] = 0.f;
  }

  // B-fragments: W[d][k], d (col) = lane&31 within d-tile.
  const float* wr0 = W + (long)arow * F_DIM;
  const float* wr1 = W + (long)(32 + arow) * F_DIM;
#pragma unroll
  for (int kk = 0; kk < 8; ++kk) {
    unsigned short h0[8], l0[8], h1[8], l1[8];
#pragma unroll
    for (int j = 0; j < 8; ++j) {
      const int f = kk * 16 + half * 8 + j;
      const float v0 = (f < F_DIM) ? wr0[f] : 0.f;
      const float v1 = (f < F_DIM) ? wr1[f] : 0.f;
      const unsigned short a = f2bf(v0);
      h0[j] = a;
      l0[j] = f2bf(v0 - bf2f(a));
      const unsigned short c = f2bf(v1);
      h1[j] = c;
      l1[j] = f2bf(v1 - bf2f(c));
    }
    bf16x8 wh0, wl0, wh1, wl1;
    __builtin_memcpy(&wh0, h0, 16);
    __builtin_memcpy(&wl0, l0, 16);
    __builtin_memcpy(&wh1, h1, 16);
    __builtin_memcpy(&wl1, l1, 16);
    acc0 = __builtin_amdgcn_mfma_f32_32x32x16_bf16(xh[kk], wh0, acc0, 0, 0, 0);
    acc0 = __builtin_amdgcn_mfma_f32_32x32x16_bf16(xh[kk], wl0, acc0, 0, 0, 0);
    acc0 = __builtin_amdgcn_mfma_f32_32x32x16_bf16(xl[kk], wh0, acc0, 0, 0, 0);
    acc1 = __builtin_amdgcn_mfma_f32_32x32x16_bf16(xh[kk], wh1, acc1, 0, 0, 0);
    acc1 = __builtin_amdgcn_mfma_f32_32x32x16_bf16(xh[kk], wl1, acc1, 0, 0, 0);
    acc1 = __builtin_amdgcn_mfma_f32_32x32x16_bf16(xl[kk], wh1, acc1, 0, 0, 0);
  }

  // Epilogue: C layout row=(r&3)+8*(r>>2)+4*half, col=lane&31.
#pragma unroll
  for (int dt = 0; dt < 2; ++dt) {
    const f32x16 acc = dt ? acc1 : acc0;
    const int d = dt * 32 + arow;
    const float bd = bias[d];
#pragma unroll
    for (int r = 0; r < 16; ++r) {
      const int grow = grow0 + (r & 3) + 8 * (r >> 2) + 4 * half;
      const float val = acc[r] + bd;
      const long o = (long)grow * 64 + d;
      if (!isK) {
        Qf[o] = val * QSCALE;
      } else {
        const unsigned short h = f2bf(val);
        kh[o] = h;
        kl[o] = f2bf(val - bf2f(h));
      }
    }
  }

  // K blocks: emit x2t[b][f 128][t 4096] straight from the hi A-fragments.
  if (isK) {
    const int growA = grow0 + arow;
    const int bb = growA >> 12;
    const int t = growA & (S_DIM - 1);
    unsigned short* xb = x2t + ((long)bb * 128) * S_DIM + t;
#pragma unroll
    for (int kk = 0; kk < 8; ++kk) {
      unsigned short hs[8];
      __builtin_memcpy(hs, &xh[kk], 16);
#pragma unroll
      for (int j = 0; j < 8; ++j) {
        const int f = kk * 16 + half * 8 + j;
        xb[(long)f * S_DIM] = hs[j];
      }
    }
  }
}

// ------------------------------------------------------------------ attention
// grid 512 x 512. block: b = bi>>7, q-rows [q0, q0+32). wave w handles key
// tiles w, w+8, ..., w+120 (16 tiles of 32 keys), private (m, l, acc) in
// log2 domain; defer-max; LDS tree merge at the end.
__global__ __launch_bounds__(512, 4) void attn_kernel(
    const float* __restrict__ Qf, const unsigned short* __restrict__ kh,
    const unsigned short* __restrict__ kl,
    const unsigned short* __restrict__ x2t, float* __restrict__ out) {
  const int tid = threadIdx.x;
  const int lane = tid & 63;
  const int wave = tid >> 6;
  const int col = lane & 31;   // q index within tile / key row for A-frag
  const int half = lane >> 5;  // k-group select
  const int bi = blockIdx.x;
  const int b = bi >> 7;
  const int q0 = (bi & 127) << 5;

  // Q B-fragments (col=q=lane&31, k = kk*16 + half*8 + j), split hi/lo
  bf16x8 qh[4], ql[4];
  {
    const float* qrow = Qf + ((long)(b * S_DIM + q0 + col)) * 64;
#pragma unroll
    for (int kk = 0; kk < 4; ++kk) {
      const int d0 = kk * 16 + half * 8;
      unsigned short hs[8], ls[8];
#pragma unroll
      for (int j = 0; j < 8; ++j) {
        const float qv = qrow[d0 + j];
        const unsigned short h = f2bf(qv);
        hs[j] = h;
        ls[j] = f2bf(qv - bf2f(h));
      }
      __builtin_memcpy(&qh[kk], hs, 16);
      __builtin_memcpy(&ql[kk], ls, 16);
    }
  }

  const uint4* khp = (const uint4*)kh + (long)b * S_DIM * 8;  // 8 uint4/key
  const uint4* klp = (const uint4*)kl + (long)b * S_DIM * 8;
  const uint4* xp = (const uint4*)x2t + (long)b * 128 * (S_DIM / 8);

  f32x16 a0, a1, a2, a3;
#pragma unroll
  for (int r = 0; r < 16; ++r) {
    a0[r] = 0.f; a1[r] = 0.f; a2[r] = 0.f; a3[r] = 0.f;
  }
  float m = -INFINITY;
  float lsum = 0.f;  // per-half partial; halves merged after the loop

  for (int it = 0; it < 16; ++it) {
    const int t0 = ((it << 3) + wave) << 5;
    const int key = t0 + col;
    uint4 khf[4], klf[4];
#pragma unroll
    for (int kk = 0; kk < 4; ++kk) {
      khf[kk] = khp[key * 8 + kk * 2 + half];
      klf[kk] = klp[key * 8 + kk * 2 + half];
    }
    // S^T = K . Q^T  (3-term split-bf16), C layout: col=q, row=key
    f32x16 st;
#pragma unroll
    for (int r = 0; r < 16; ++r) st[r] = 0.f;
#pragma unroll
    for (int kk = 0; kk < 4; ++kk) {
      bf16x8 kv, lv;
      __builtin_memcpy(&kv, &khf[kk], 16);
      __builtin_memcpy(&lv, &klf[kk], 16);
      st = __builtin_amdgcn_mfma_f32_32x32x16_bf16(kv, qh[kk], st, 0, 0, 0);
      st = __builtin_amdgcn_mfma_f32_32x32x16_bf16(kv, ql[kk], st, 0, 0, 0);
      st = __builtin_amdgcn_mfma_f32_32x32x16_bf16(lv, qh[kk], st, 0, 0, 0);
    }
    // online softmax (log2 domain): lane's 16 regs = 16 keys of its q-col;
    // other 16 keys are in lane^32 -> one shfl_xor completes the row max.
    float pmax = st[0];
#pragma unroll
    for (int r = 1; r < 16; ++r) pmax = fmaxf(pmax, st[r]);
    pmax = fmaxf(pmax, __shfl_xor(pmax, 32));
    if (__any(pmax > m + THR)) {  // defer-max: rescale rarely
      const float mnew = fmaxf(m, pmax);
      const float sc = exp2_fast(m - mnew);
      lsum *= sc;
#pragma unroll
      for (int r = 0; r < 16; ++r) {
        a0[r] *= sc; a1[r] *= sc; a2[r] *= sc; a3[r] *= sc;
      }
      m = mnew;
    }
    float p[16];
    float ts = 0.f;
#pragma unroll
    for (int r = 0; r < 16; ++r) {
      p[r] = exp2_fast(st[r] - m);
      ts += p[r];
    }
    lsum += ts;
    // pack P rows (C-layout regs) into PV B-fragments:
    // frag[kk] elem j needs reg 8kk+4h+(j&3) from half (j>=4) of same col
    // -> exactly one permlane32_swap pair per kk.
    unsigned pg[4][2];
#pragma unroll
    for (int g = 0; g < 4; ++g) {
      pg[g][0] = cvt_pk_bf16(p[4 * g + 0], p[4 * g + 1]);
      pg[g][1] = cvt_pk_bf16(p[4 * g + 2], p[4 * g + 3]);
    }
#pragma unroll
    for (int kk = 0; kk < 2; ++kk) {
      unsigned x0 = pg[2 * kk][0], y0 = pg[2 * kk + 1][0];
      unsigned x1 = pg[2 * kk][1], y1 = pg[2 * kk + 1][1];
      asm("v_permlane32_swap_b32 %0, %1" : "+v"(x0), "+v"(y0));
      asm("v_permlane32_swap_b32 %0, %1" : "+v"(x1), "+v"(y1));
      const bf16x8 pf = mk_bf16x8(x0, x1, y0, y1);
      const int tof = (t0 + kk * 16 + half * 8) >> 3;  // uint4 idx in f-row
      bf16x8 xf;
      uint4 xv;
      xv = xp[(0 * 32 + col) * (S_DIM / 8) + tof];
      __builtin_memcpy(&xf, &xv, 16);
      a0 = __builtin_amdgcn_mfma_f32_32x32x16_bf16(xf, pf, a0, 0, 0, 0);
      xv = xp[(1 * 32 + col) * (S_DIM / 8) + tof];
      __builtin_memcpy(&xf, &xv, 16);
      a1 = __builtin_amdgcn_mfma_f32_32x32x16_bf16(xf, pf, a1, 0, 0, 0);
      xv = xp[(2 * 32 + col) * (S_DIM / 8) + tof];
      __builtin_memcpy(&xf, &xv, 16);
      a2 = __builtin_amdgcn_mfma_f32_32x32x16_bf16(xf, pf, a2, 0, 0, 0);
      xv = xp[(3 * 32 + col) * (S_DIM / 8) + tof];
      __builtin_memcpy(&xf, &xv, 16);
      a3 = __builtin_amdgcn_mfma_f32_32x32x16_bf16(xf, pf, a3, 0, 0, 0);
    }
  }
  lsum += __shfl_xor(lsum, 32);

  // -------- merge the 8 waves' partial (m, l, acc^T): tree in LDS.
  __shared__ float mbuf[8][32];
  __shared__ float lbuf[8][32];
  __shared__ float bufs[2 * 128 * 33];
  if (lane < 32) {
    mbuf[wave][col] = m;
    lbuf[wave][col] = lsum;
  }
  __syncthreads();
  float mstar = mbuf[0][col];
#pragma unroll
  for (int w = 1; w < 8; ++w) mstar = fmaxf(mstar, mbuf[w][col]);
  const float wsc = exp2_fast(m - mstar);

  float* buf = bufs + (wave >> 2) * (128 * 33);
  const int ph = wave & 3;
  auto emit = [&](const f32x16& av, int fb, bool first) {
#pragma unroll
    for (int r = 0; r < 16; ++r) {
      const int f = fb * 32 + (r & 3) + 8 * (r >> 2) + 4 * half;
      const float v = av[r] * wsc;
      if (first) buf[f * 33 + col] = v;
      else buf[f * 33 + col] += v;
    }
  };
  for (int p = 0; p < 4; ++p) {
    if (ph == p) {
      const bool first = (p == 0);
      emit(a0, 0, first);
      emit(a1, 1, first);
      emit(a2, 2, first);
      emit(a3, 3, first);
    }
    __syncthreads();
  }

  // readout: 512 threads, q = tid>>4 (32), fg = tid&15, 8 f each.
  const int q = tid >> 4;
  const int fg = tid & 15;
  float ms2 = mbuf[0][q];
#pragma unroll
  for (int w = 1; w < 8; ++w) ms2 = fmaxf(ms2, mbuf[w][q]);
  float lst = 0.f;
#pragma unroll
  for (int w = 0; w < 8; ++w) lst += lbuf[w][q] * exp2_fast(mbuf[w][q] - ms2);
  const float inv = 1.0f / lst;
  float* ob = out + ((long)(b * S_DIM + q0 + q)) * F_DIM;
#pragma unroll
  for (int j = 0; j < 8; ++j) {
    const int f = fg * 8 + j;
    if (f < F_DIM) ob[f] = (bufs[f * 33 + q] + bufs[128 * 33 + f * 33 + q]) * inv;
  }
}

extern "C" void kernel_launch(void* const* d_in, const int* in_sizes, int n_in,
                              void* d_out, int out_size, void* d_ws,
                              size_t ws_size, hipStream_t stream) {
  const float* x1 = (const float*)d_in[0];
  const float* x2 = (const float*)d_in[1];
  const float* W = (const float*)d_in[2];
  const float* bias = (const float*)d_in[3];
  float* out = (float*)d_out;

  char* ws = (char*)d_ws;
  float* Qf = (float*)ws;                                    // 4 MB
  unsigned short* kh = (unsigned short*)(ws + (4l << 20));   // 2 MB
  unsigned short* kl = (unsigned short*)(ws + (6l << 20));   // 2 MB
  unsigned short* x2t = (unsigned short*)(ws + (8l << 20));  // 4 MB

  hipLaunchKernelGGL(proj_kernel, dim3(256), dim3(256), 0, stream, x1, x2, W,
                     bias, Qf, kh, kl, x2t);
  hipLaunchKernelGGL(attn_kernel, dim3(512), dim3(512), 0, stream, Qf, kh, kl,
                     x2t, out);
}

// Round 3
// 76.447 us; speedup vs baseline: 2.3247x; 2.2213x over previous
//
#include <hip/hip_runtime.h>
#include <hip/hip_bf16.h>

// Fused attention: q = x1@W^T+b, k = x2@W^T+b, scores = (q k^T)*8,
// p = softmax(scores), out = p @ x2.  B=4, S=T=4096, F=127, D=64, fp32 io.
//
// Round 2: kill the gather-transaction storm. K and x2 are stored in
// MFMA-fragment order (1 KB contiguous per wave fragment load):
//  - proj_kernel: split-bf16 MFMA GEMM. Q -> fp32 linear (8*log2e folded).
//    K -> khf/klf fragment layout via an LDS bounce (stride-66 pad).
//  - x2repack_kernel: x2 fp32 -> x2tf bf16 PV-A-fragment layout.
//  - attn_kernel: 256 thr / 4 waves, registers-only main loop, next-tile
//    K prefetch, log2-domain online softmax with defer-max, LDS merge.
//
// ws layout: Qf32 [0,4MB) | khf [4,6) | klf [6,8) | x2tf [8,12)

typedef __bf16 bf16x8 __attribute__((ext_vector_type(8)));
typedef float f32x16 __attribute__((ext_vector_type(16)));

#define S_DIM 4096
#define F_DIM 127
#define QSCALE 11.5415603271f  // 8 * log2(e)
#define THR 11.0f              // defer-max threshold (log2 units)

static __device__ __forceinline__ unsigned short f2bf(float f) {
  unsigned u = __float_as_uint(f);
  unsigned r = u + 0x7FFFu + ((u >> 16) & 1u);  // RNE, no NaN in our data
  return (unsigned short)(r >> 16);
}
static __device__ __forceinline__ float bf2f(unsigned short h) {
  return __uint_as_float(((unsigned)h) << 16);
}
static __device__ __forceinline__ unsigned cvt_pk_bf16(float lo, float hi) {
  unsigned r;
  asm("v_cvt_pk_bf16_f32 %0, %1, %2" : "=v"(r) : "v"(lo), "v"(hi));
  return r;
}
static __device__ __forceinline__ float exp2_fast(float x) {
  float r;
  asm("v_exp_f32 %0, %1" : "=v"(r) : "v"(x));
  return r;
}
static __device__ __forceinline__ bf16x8 mk_bf16x8(unsigned w0, unsigned w1,
                                                   unsigned w2, unsigned w3) {
  unsigned t[4] = {w0, w1, w2, w3};
  bf16x8 r;
  __builtin_memcpy(&r, t, 16);
  return r;
}
static __device__ __forceinline__ bf16x8 u4_bf16x8(uint4 v) {
  bf16x8 r;
  __builtin_memcpy(&r, &v, 16);
  return r;
}

// ---------------------------------------------------------------- projection
// grid 256 x 256. blocks [0,128) -> Q from x1, [128,256) -> K from x2.
// Block = 128 rows (4 waves x 32). K epilogue bounces through LDS to emit
// khf/klf in QK-A-fragment order: khf[b][tile][kk][lane] = one uint4.
__global__ __launch_bounds__(256) void proj_kernel(
    const float* __restrict__ x1, const float* __restrict__ x2,
    const float* __restrict__ W, const float* __restrict__ bias,
    float* __restrict__ Qf, uint4* __restrict__ khf, uint4* __restrict__ klf) {
  __shared__ unsigned kstage[4][32 * 66];  // stride 66: 2-way banks (free)
  const int tid = threadIdx.x;
  const int wave = tid >> 6;
  const int lane = tid & 63;
  const int arow = lane & 31;
  const int half = lane >> 5;
  const int bi = blockIdx.x;
  const bool isK = bi >= 128;
  const float* x = isK ? x2 : x1;
  const int grow0 = (bi & 127) * 128 + wave * 32;
  const float* xrow = x + (long)(grow0 + arow) * F_DIM;

  // A-fragments: x[row][k], row=lane&31, k = kk*16 + half*8 + j. Split hi/lo.
  bf16x8 xh[8], xl[8];
#pragma unroll
  for (int kk = 0; kk < 8; ++kk) {
    unsigned short hs[8], ls[8];
#pragma unroll
    for (int j = 0; j < 8; ++j) {
      const int f = kk * 16 + half * 8 + j;
      const float v = (f < F_DIM) ? xrow[f] : 0.f;
      const unsigned short h = f2bf(v);
      hs[j] = h;
      ls[j] = f2bf(v - bf2f(h));
    }
    __builtin_memcpy(&xh[kk], hs, 16);
    __builtin_memcpy(&xl[kk], ls, 16);
  }

  f32x16 acc0, acc1;
#pragma unroll
  for (int r = 0; r < 16; ++r) {
    acc0[r] = 0.f;
    acc1[r] = 0.f;
  }

  const float* wr0 = W + (long)arow * F_DIM;
  const float* wr1 = W + (long)(32 + arow) * F_DIM;
#pragma unroll
  for (int kk = 0; kk < 8; ++kk) {
    unsigned short h0[8], l0[8], h1[8], l1[8];
#pragma unroll
    for (int j = 0; j < 8; ++j) {
      const int f = kk * 16 + half * 8 + j;
      const float v0 = (f < F_DIM) ? wr0[f] : 0.f;
      const float v1 = (f < F_DIM) ? wr1[f] : 0.f;
      const unsigned short a = f2bf(v0);
      h0[j] = a;
      l0[j] = f2bf(v0 - bf2f(a));
      const unsigned short c = f2bf(v1);
      h1[j] = c;
      l1[j] = f2bf(v1 - bf2f(c));
    }
    bf16x8 wh0, wl0, wh1, wl1;
    __builtin_memcpy(&wh0, h0, 16);
    __builtin_memcpy(&wl0, l0, 16);
    __builtin_memcpy(&wh1, h1, 16);
    __builtin_memcpy(&wl1, l1, 16);
    acc0 = __builtin_amdgcn_mfma_f32_32x32x16_bf16(xh[kk], wh0, acc0, 0, 0, 0);
    acc0 = __builtin_amdgcn_mfma_f32_32x32x16_bf16(xh[kk], wl0, acc0, 0, 0, 0);
    acc0 = __builtin_amdgcn_mfma_f32_32x32x16_bf16(xl[kk], wh0, acc0, 0, 0, 0);
    acc1 = __builtin_amdgcn_mfma_f32_32x32x16_bf16(xh[kk], wh1, acc1, 0, 0, 0);
    acc1 = __builtin_amdgcn_mfma_f32_32x32x16_bf16(xh[kk], wl1, acc1, 0, 0, 0);
    acc1 = __builtin_amdgcn_mfma_f32_32x32x16_bf16(xl[kk], wh1, acc1, 0, 0, 0);
  }

  // Epilogue. C layout: row=(r&3)+8*(r>>2)+4*half (= key in tile), col=d.
  unsigned* kst = kstage[wave];
#pragma unroll
  for (int dt = 0; dt < 2; ++dt) {
    const f32x16 acc = dt ? acc1 : acc0;
    const int d = dt * 32 + arow;
    const float bd = bias[d];
#pragma unroll
    for (int r = 0; r < 16; ++r) {
      const int row = (r & 3) + 8 * (r >> 2) + 4 * half;
      const float val = acc[r] + bd;
      if (!isK) {
        Qf[(long)(grow0 + row) * 64 + d] = val * QSCALE;
      } else {
        const unsigned short h = f2bf(val);
        const unsigned short lo = f2bf(val - bf2f(h));
        kst[row * 66 + d] = (unsigned)h | ((unsigned)lo << 16);
      }
    }
  }

  if (isK) {
    const int b = grow0 >> 12;
    const int tile = (grow0 & (S_DIM - 1)) >> 5;
    uint4* ko = khf + ((long)(b * 128 + tile) * 4) * 64 + lane;
    uint4* lo_ = klf + ((long)(b * 128 + tile) * 4) * 64 + lane;
#pragma unroll
    for (int kk = 0; kk < 4; ++kk) {
      const int d0 = kk * 16 + half * 8;
      unsigned w[8];
#pragma unroll
      for (int j = 0; j < 8; ++j) w[j] = kst[arow * 66 + d0 + j];
      unsigned hw[4], lw[4];
#pragma unroll
      for (int g = 0; g < 4; ++g) {
        hw[g] = (w[2 * g] & 0xffffu) | (w[2 * g + 1] << 16);
        lw[g] = (w[2 * g] >> 16) | (w[2 * g + 1] & 0xffff0000u);
      }
      ko[kk * 64] = make_uint4(hw[0], hw[1], hw[2], hw[3]);
      lo_[kk * 64] = make_uint4(lw[0], lw[1], lw[2], lw[3]);
    }
  }
}

// ------------------------------------------------------ x2 -> PV-A fragments
// grid 1024 x 256. block: b = bi>>8, tt = bi&255 (16-t tile). Thread (fb,l)
// emits x2tf[b][tt][fb][l] = bf16(x2[b][tt*16+(l>>5)*8+j][fb*32+(l&31)]).
__global__ __launch_bounds__(256) void x2repack_kernel(
    const float* __restrict__ x2, uint4* __restrict__ x2tf) {
  const int tid = threadIdx.x;
  const int bi = blockIdx.x;
  const int b = bi >> 8;
  const int tt = bi & 255;
  const int fb = tid >> 6;
  const int l = tid & 63;
  const int t0 = tt * 16 + ((l >> 5) << 3);
  const int f = fb * 32 + (l & 31);
  const float* src = x2 + ((long)b * S_DIM + t0) * F_DIM + f;
  unsigned short e[8];
#pragma unroll
  for (int j = 0; j < 8; ++j)
    e[j] = (f < F_DIM) ? f2bf(src[(long)j * F_DIM]) : (unsigned short)0;
  unsigned w0 = (unsigned)e[0] | ((unsigned)e[1] << 16);
  unsigned w1 = (unsigned)e[2] | ((unsigned)e[3] << 16);
  unsigned w2 = (unsigned)e[4] | ((unsigned)e[5] << 16);
  unsigned w3 = (unsigned)e[6] | ((unsigned)e[7] << 16);
  x2tf[((long)(b * 256 + tt) * 4 + fb) * 64 + l] = make_uint4(w0, w1, w2, w3);
}

// ------------------------------------------------------------------ attention
// grid 512 x 256. block: b = bi>>7, q-rows [q0, q0+32). wave w handles key
// tiles w, w+4, ..., w+124 (32 iters), private (m, l, acc) in log2 domain;
// defer-max; next-tile K prefetch; LDS merge at the end.
__global__ __launch_bounds__(256, 2) void attn_kernel(
    const float* __restrict__ Qf, const uint4* __restrict__ khf,
    const uint4* __restrict__ klf, const uint4* __restrict__ x2tf,
    float* __restrict__ out) {
  const int tid = threadIdx.x;
  const int lane = tid & 63;
  const int wave = tid >> 6;
  const int col = lane & 31;   // q index within tile
  const int half = lane >> 5;
  const int bi = blockIdx.x;
  const int b = bi >> 7;
  const int q0 = (bi & 127) << 5;

  // Q B-fragments (col=q=lane&31, k = kk*16 + half*8 + j), split hi/lo
  bf16x8 qh[4], ql[4];
  {
    const float* qrow = Qf + ((long)(b * S_DIM + q0 + col)) * 64;
#pragma unroll
    for (int kk = 0; kk < 4; ++kk) {
      const int d0 = kk * 16 + half * 8;
      unsigned short hs[8], ls[8];
#pragma unroll
      for (int j = 0; j < 8; ++j) {
        const float qv = qrow[d0 + j];
        const unsigned short h = f2bf(qv);
        hs[j] = h;
        ls[j] = f2bf(qv - bf2f(h));
      }
      __builtin_memcpy(&qh[kk], hs, 16);
      __builtin_memcpy(&ql[kk], ls, 16);
    }
  }

  const uint4* khfp = khf + (long)b * 128 * 4 * 64;
  const uint4* klfp = klf + (long)b * 128 * 4 * 64;
  const uint4* xfp = x2tf + (long)b * 256 * 4 * 64;

  f32x16 a0, a1, a2, a3;
#pragma unroll
  for (int r = 0; r < 16; ++r) {
    a0[r] = 0.f; a1[r] = 0.f; a2[r] = 0.f; a3[r] = 0.f;
  }
  float m = -INFINITY;
  float lsum = 0.f;  // per-half partial; halves merged after the loop

  uint4 KC[8], KN[8];
#pragma unroll
  for (int kk = 0; kk < 4; ++kk) {
    KC[kk] = khfp[(wave * 4 + kk) * 64 + lane];
    KC[4 + kk] = klfp[(wave * 4 + kk) * 64 + lane];
  }

#pragma unroll 2
  for (int it = 0; it < 32; ++it) {
    const int tile = (it << 2) + wave;
    // issue PV operand loads (latency hides under QK + softmax)
    uint4 xv[8];
#pragma unroll
    for (int kf = 0; kf < 2; ++kf)
#pragma unroll
      for (int fb = 0; fb < 4; ++fb)
        xv[kf * 4 + fb] = xfp[((tile * 2 + kf) * 4 + fb) * 64 + lane];
    // prefetch next K tile (clamped; redundant load on last iter is harmless)
    int tn = tile + 4;
    if (tn > 127) tn = 127;
#pragma unroll
    for (int kk = 0; kk < 4; ++kk) {
      KN[kk] = khfp[(tn * 4 + kk) * 64 + lane];
      KN[4 + kk] = klfp[(tn * 4 + kk) * 64 + lane];
    }
    // S^T = K . Q^T  (3-term split-bf16), C layout: col=q, row=key
    f32x16 st;
#pragma unroll
    for (int r = 0; r < 16; ++r) st[r] = 0.f;
#pragma unroll
    for (int kk = 0; kk < 4; ++kk) {
      const bf16x8 kv = u4_bf16x8(KC[kk]);
      const bf16x8 lv = u4_bf16x8(KC[4 + kk]);
      st = __builtin_amdgcn_mfma_f32_32x32x16_bf16(kv, qh[kk], st, 0, 0, 0);
      st = __builtin_amdgcn_mfma_f32_32x32x16_bf16(kv, ql[kk], st, 0, 0, 0);
      st = __builtin_amdgcn_mfma_f32_32x32x16_bf16(lv, qh[kk], st, 0, 0, 0);
    }
    // online softmax (log2 domain), defer-max
    float pmax = st[0];
#pragma unroll
    for (int r = 1; r < 16; ++r) pmax = fmaxf(pmax, st[r]);
    pmax = fmaxf(pmax, __shfl_xor(pmax, 32));
    if (__any(pmax > m + THR)) {
      const float mnew = fmaxf(m, pmax);
      const float sc = exp2_fast(m - mnew);
      lsum *= sc;
#pragma unroll
      for (int r = 0; r < 16; ++r) {
        a0[r] *= sc; a1[r] *= sc; a2[r] *= sc; a3[r] *= sc;
      }
      m = mnew;
    }
    float ts = 0.f;
    unsigned pg[4][2];
#pragma unroll
    for (int g = 0; g < 4; ++g) {
      const float p0 = exp2_fast(st[4 * g + 0] - m);
      const float p1 = exp2_fast(st[4 * g + 1] - m);
      const float p2 = exp2_fast(st[4 * g + 2] - m);
      const float p3 = exp2_fast(st[4 * g + 3] - m);
      ts += (p0 + p1) + (p2 + p3);
      pg[g][0] = cvt_pk_bf16(p0, p1);
      pg[g][1] = cvt_pk_bf16(p2, p3);
    }
    lsum += ts;
    // pack P rows into PV B-fragments (one permlane32_swap pair per kk)
#pragma unroll
    for (int kk = 0; kk < 2; ++kk) {
      unsigned x0 = pg[2 * kk][0], y0 = pg[2 * kk + 1][0];
      unsigned x1 = pg[2 * kk][1], y1 = pg[2 * kk + 1][1];
      asm("v_permlane32_swap_b32 %0, %1" : "+v"(x0), "+v"(y0));
      asm("v_permlane32_swap_b32 %0, %1" : "+v"(x1), "+v"(y1));
      const bf16x8 pf = mk_bf16x8(x0, x1, y0, y1);
      a0 = __builtin_amdgcn_mfma_f32_32x32x16_bf16(u4_bf16x8(xv[kk * 4 + 0]),
                                                   pf, a0, 0, 0, 0);
      a1 = __builtin_amdgcn_mfma_f32_32x32x16_bf16(u4_bf16x8(xv[kk * 4 + 1]),
                                                   pf, a1, 0, 0, 0);
      a2 = __builtin_amdgcn_mfma_f32_32x32x16_bf16(u4_bf16x8(xv[kk * 4 + 2]),
                                                   pf, a2, 0, 0, 0);
      a3 = __builtin_amdgcn_mfma_f32_32x32x16_bf16(u4_bf16x8(xv[kk * 4 + 3]),
                                                   pf, a3, 0, 0, 0);
    }
#pragma unroll
    for (int i = 0; i < 8; ++i) KC[i] = KN[i];
  }
  lsum += __shfl_xor(lsum, 32);

  // -------- merge the 4 waves' partial (m, l, acc^T) in LDS
  __shared__ float mbuf[4][32];
  __shared__ float lbuf[4][32];
  __shared__ float accbuf[128 * 33];
  if (lane < 32) {
    mbuf[wave][col] = m;
    lbuf[wave][col] = lsum;
  }
  __syncthreads();
  const float mstar = fmaxf(fmaxf(mbuf[0][col], mbuf[1][col]),
                            fmaxf(mbuf[2][col], mbuf[3][col]));
  const float wsc = exp2_fast(m - mstar);
  for (int w = 0; w < 4; ++w) {
    if (wave == w) {
#pragma unroll
      for (int fb = 0; fb < 4; ++fb) {
        const f32x16 av = (fb == 0) ? a0 : (fb == 1) ? a1 : (fb == 2) ? a2 : a3;
#pragma unroll
        for (int r = 0; r < 16; ++r) {
          const int f = fb * 32 + (r & 3) + 8 * (r >> 2) + 4 * half;
          const float v = av[r] * wsc;
          if (w == 0) accbuf[f * 33 + col] = v;
          else accbuf[f * 33 + col] += v;
        }
      }
    }
    __syncthreads();
  }
  const int q = tid >> 3;
  const int fg = tid & 7;
  const float ms2 = fmaxf(fmaxf(mbuf[0][q], mbuf[1][q]),
                          fmaxf(mbuf[2][q], mbuf[3][q]));
  float lst = 0.f;
#pragma unroll
  for (int w = 0; w < 4; ++w) lst += lbuf[w][q] * exp2_fast(mbuf[w][q] - ms2);
  const float inv = 1.0f / lst;
  float* ob = out + ((long)(b * S_DIM + q0 + q)) * F_DIM;
#pragma unroll
  for (int j = 0; j < 16; ++j) {
    const int f = fg * 16 + j;
    if (f < F_DIM) ob[f] = accbuf[f * 33 + q] * inv;
  }
}

extern "C" void kernel_launch(void* const* d_in, const int* in_sizes, int n_in,
                              void* d_out, int out_size, void* d_ws,
                              size_t ws_size, hipStream_t stream) {
  const float* x1 = (const float*)d_in[0];
  const float* x2 = (const float*)d_in[1];
  const float* W = (const float*)d_in[2];
  const float* bias = (const float*)d_in[3];
  float* out = (float*)d_out;

  char* ws = (char*)d_ws;
  float* Qf = (float*)ws;                      // 4 MB
  uint4* khf = (uint4*)(ws + (4l << 20));      // 2 MB
  uint4* klf = (uint4*)(ws + (6l << 20));      // 2 MB
  uint4* x2tf = (uint4*)(ws + (8l << 20));     // 4 MB

  hipLaunchKernelGGL(proj_kernel, dim3(256), dim3(256), 0, stream, x1, x2, W,
                     bias, Qf, khf, klf);
  hipLaunchKernelGGL(x2repack_kernel, dim3(1024), dim3(256), 0, stream, x2,
                     x2tf);
  hipLaunchKernelGGL(attn_kernel, dim3(512), dim3(256), 0, stream, Qf, khf,
                     klf, x2tf, out);
}